// Round 19
// baseline (177.504 us; speedup 1.0000x reference)
//
#include <hip/hip_runtime.h>
#include <math.h>

// Problem constants: B=16, K=4, T=64, N=128, F=16, H=32, NH=8, GH=32
// Sequences: 12288 = 2048 anchor + 2048 pos + 8192 neg. Graphs: 96 = 16+16+64.

typedef __bf16 bf16x8 __attribute__((ext_vector_type(8)));
typedef float  f32x4  __attribute__((ext_vector_type(4)));
typedef unsigned int u32x4 __attribute__((ext_vector_type(4)));

__device__ __forceinline__ float fast_rcp(float x) { return __builtin_amdgcn_rcpf(x); }
__device__ __forceinline__ float sigm(float x)     { return fast_rcp(1.f + __expf(-x)); }
__device__ __forceinline__ float tanh_fast(float x){ return fmaf(2.f, fast_rcp(1.f + __expf(-2.f * x)), -1.f); }

#define KEEP4(x) asm volatile("" : "+v"(x))

// ---------------------------------------------------------------------------
// LSTM via MFMA, 8-wave UNIT-split with in-wave gate exchange (1 barrier/step).
// Block = 512 threads owns 16 sequences. Wave w owns units 4w..4w+3; its 16
// MFMA columns = 4 units x 4 gates: col c = gate*4 + ul, weight row =
// gate*32 + 4w + ul. After 3 MFMAs, all 4 gates of each (seq,unit) live
// INSIDE the wave (C/D: col=lane&15, row=(lane>>4)*4+reg [HW-verified]), so
// a 16-shfl exchange (static reg idx, predicated accept) replaces the old
// Zl LDS round-trip + one of the two barriers. Lane owns (seq=lane>>2,
// ul=lane&3): 10 trans ops, h -> Hbuf (swizzled), ONE barrier, repeat.
// 3 MFMAs/tile: ax*wih_hi + ahi*whh_hi + ahi*whh_lo (h_lo dropped, ~1e-3).
// ---------------------------------------------------------------------------
__global__ __launch_bounds__(512, 1) void lstm_mfma_kernel(
    const float* __restrict__ anchor, const float* __restrict__ pos,
    const float* __restrict__ neg, const float* __restrict__ Wih,
    const float* __restrict__ Whh, const float* __restrict__ bias,
    float* __restrict__ hn)
{
    __shared__ unsigned int Hbuf[2][512];   // [dbuf][16 m][32 j], 4 KB
    const int tid  = threadIdx.x;
    const int w    = tid >> 6;      // wave id: owns units 4w..4w+3
    const int lane = tid & 63;
    const int l15  = lane & 15;
    const int g4   = lane >> 4;

    #pragma unroll
    for (int i = 0; i < 2; ++i) ((unsigned int*)Hbuf)[tid + i * 512] = 0u;

    // B-fragment: col c=l15 -> gate=c>>2, unit=4w+(c&3), wrow=gate*32+unit
    const int wrow = (l15 >> 2) * 32 + 4 * w + (l15 & 3);
    u32x4 whhH, whhL, wihH;
    {
        union { u32x4 u; bf16x8 v; } th, tl, ti;
        const float* wr = Whh + wrow * 32 + g4 * 8;
        #pragma unroll
        for (int i = 0; i < 8; ++i) {
            float wv = wr[i];
            __bf16 hi = (__bf16)wv;
            th.v[i] = hi;
            tl.v[i] = (__bf16)(wv - (float)hi);
        }
        if (g4 < 2) {
            const float* wr2 = Wih + wrow * 16 + g4 * 8;
            #pragma unroll
            for (int i = 0; i < 8; ++i) ti.v[i] = (__bf16)wr2[i];
        } else {
            #pragma unroll
            for (int i = 0; i < 8; ++i) ti.v[i] = (__bf16)0.f;
        }
        whhH = th.u; whhL = tl.u; wihH = ti.u;
    }
    KEEP4(whhH); KEEP4(whhL); KEEP4(wihH);

    // Activation role: lane owns (seq = lane>>2, unit = 4w + (lane&3))
    const int aseq  = lane >> 2;
    const int aunit = 4 * w + (lane & 3);
    const float bi = bias[aunit],       bf_ = bias[32 + aunit];
    const float bg = bias[64 + aunit],  bo  = bias[96 + aunit];

    // x source: seq = blk*16 + l15 (all 8 waves load the same x -> L1 hits)
    const int s = blockIdx.x * 16 + l15;
    const float* xbase; int sl;
    if (s < 2048)      { xbase = anchor; sl = s; }
    else if (s < 4096) { xbase = pos;    sl = s - 2048; }
    else               { xbase = neg;    sl = s - 4096; }
    const bool xact = (g4 < 2);
    const float* xp = xbase + (sl >> 7) * 131072 + (sl & 127) * 16 + (xact ? g4 * 8 : 0);

    const float4 z4 = make_float4(0.f, 0.f, 0.f, 0.f);
    float4 xaA = z4, xbA = z4, xaB = z4, xbB = z4;
    if (xact) {
        xaA = *(const float4*)(xp);        xbA = *(const float4*)(xp + 4);
        xaB = *(const float4*)(xp + 2048); xbB = *(const float4*)(xp + 2052);
    }

    float cstA = 0.f, hA = 0.f;

    // Addresses.  Hbuf chunk swizzle: physical chunk = logical ^ (row & 7).
    const int c0  = g4 * 2;
    const int swz = l15 & 7;
    const int ro0 = l15 * 32 + ((c0 ^ swz) << 2);
    const int ro1 = l15 * 32 + (((c0 + 1) ^ swz) << 2);
    const int hw  = aseq * 32 + (((aunit >> 2) ^ (aseq & 7)) << 2) + (aunit & 3);
    const int sbase = (lane & 0x30) + (lane & 3);   // (seq>>2)*16 + ul
    const int myr   = (lane >> 2) & 3;              // seq & 3
    int cur = 0;
    __syncthreads();

    #define LSTM_STEP(XA, XB)                                                          \
    {                                                                                  \
        bf16x8 ax;                                                                     \
        ax[0]=(__bf16)XA.x; ax[1]=(__bf16)XA.y; ax[2]=(__bf16)XA.z; ax[3]=(__bf16)XA.w;\
        ax[4]=(__bf16)XB.x; ax[5]=(__bf16)XB.y; ax[6]=(__bf16)XB.z; ax[7]=(__bf16)XB.w;\
        uint4 v0 = *(const uint4*)(Hbuf[cur] + ro0);                                   \
        uint4 v1 = *(const uint4*)(Hbuf[cur] + ro1);                                   \
        union { unsigned int u[4]; bf16x8 v; } ahi;                                    \
        ahi.u[0] = __builtin_amdgcn_perm(v0.y, v0.x, 0x05040100u);                     \
        ahi.u[1] = __builtin_amdgcn_perm(v0.w, v0.z, 0x05040100u);                     \
        ahi.u[2] = __builtin_amdgcn_perm(v1.y, v1.x, 0x05040100u);                     \
        ahi.u[3] = __builtin_amdgcn_perm(v1.w, v1.z, 0x05040100u);                     \
        f32x4 a = __builtin_amdgcn_mfma_f32_16x16x32_bf16(                             \
            ax, __builtin_bit_cast(bf16x8, wihH), (f32x4)(0.f), 0, 0, 0);              \
        a = __builtin_amdgcn_mfma_f32_16x16x32_bf16(                                   \
            ahi.v, __builtin_bit_cast(bf16x8, whhH), a, 0, 0, 0);                      \
        a = __builtin_amdgcn_mfma_f32_16x16x32_bf16(                                   \
            ahi.v, __builtin_bit_cast(bf16x8, whhL), a, 0, 0, 0);                      \
        /* in-wave gate exchange: z[seq][gate*4+ul] is in lane sbase+gate*4, */        \
        /* reg seq&3. 16 shfl with STATIC reg index, predicated accept.      */        \
        float zi = 0.f, zf = 0.f, zg_ = 0.f, zo = 0.f;                                 \
        _Pragma("unroll")                                                              \
        for (int r = 0; r < 4; ++r) {                                                  \
            float t0 = __shfl(a[r], sbase);                                            \
            float t1 = __shfl(a[r], sbase + 4);                                        \
            float t2 = __shfl(a[r], sbase + 8);                                        \
            float t3 = __shfl(a[r], sbase + 12);                                       \
            if (myr == r) { zi = t0; zf = t1; zg_ = t2; zo = t3; }                     \
        }                                                                              \
        zi += bi; zf += bf_; zg_ += bg; zo += bo;                                      \
        float cn = fmaf(sigm(zf), cstA, sigm(zi) * tanh_fast(zg_));                    \
        cstA = cn;                                                                     \
        hA = sigm(zo) * tanh_fast(cn);                                                 \
        Hbuf[cur ^ 1][hw] = (unsigned int)__builtin_bit_cast(unsigned short,           \
                                                             (__bf16)hA);             \
        __syncthreads();                                                               \
        cur ^= 1;                                                                      \
    }

    for (int t = 0; t < 64; t += 2) {
        float4 cA1 = xaA, cA2 = xbA;
        if (xact && t + 2 < 64) {
            const float* p = xp + (t + 2) * 2048;
            xaA = *(const float4*)(p); xbA = *(const float4*)(p + 4);
        }
        LSTM_STEP(cA1, cA2);

        float4 cB1 = xaB, cB2 = xbB;
        if (xact && t + 3 < 64) {
            const float* p = xp + (t + 3) * 2048;
            xaB = *(const float4*)(p); xbB = *(const float4*)(p + 4);
        }
        LSTM_STEP(cB1, cB2);
    }
    #undef LSTM_STEP

    // epilogue: each lane writes its (seq, unit)
    hn[(blockIdx.x * 16 + aseq) * 32 + aunit] = hA;
}

// FS layout: 4-float shim every 32 rows -> concurrently-read rows land in
// distinct bank groups for all splits used below.
__device__ __forceinline__ int fsoff(int n) { return n * 36 + ((n >> 5) << 2); }

// ---------------------------------------------------------------------------
// GATv2 layer 1: 768 blocks = (graph, head); 256 threads.
// Phase A on MFMA: 4 waves; wave w owns (matrix = w>>1: 0=FS,1=FD,
// col-half = (w&1)*16). B = W columns split bf16 hi/lo; per 16-row tile:
// 2x float4 h loads -> hi/lo A-fragments -> 3 MFMAs (drop lo*lo) -> 4 scalar
// LDS stores via C/D map (col=lane&15, row=(lane>>4)*4+r) [HW-verified].
// Fused pass: TWO d-rows per thread sharing one fa row read; lrelu split
// a.lrelu(e) = 0.6 a.e + 0.4 a.|e|; no-max-shift exp is safe.
// ---------------------------------------------------------------------------
__global__ __launch_bounds__(256, 2) void gat1_kernel(
    const float* __restrict__ hn, const float* __restrict__ W1s,
    const float* __restrict__ W1d, const float* __restrict__ a1,
    const float* __restrict__ b1, float* __restrict__ h1heads)
{
    const int g = blockIdx.x >> 3, hd = blockIdx.x & 7;
    __shared__ float FSf[128 * 36 + 16];
    __shared__ float FD[128][36];
    __shared__ float AVr[32];
    __shared__ float As06[128];
    __shared__ float Ad06[128];
    const int tid = threadIdx.x;

    if (tid < 32) AVr[tid] = a1[hd * 32 + tid];

    // Phase A via MFMA
    {
        const int wv = tid >> 6, lane = tid & 63;
        const int l15 = lane & 15, g4 = lane >> 4;
        const int colbase = (wv & 1) * 16;
        const bool isFD = (wv >> 1) != 0;
        const float* Wmat = isFD ? W1d : W1s;

        u32x4 bH, bL;
        {
            union { u32x4 u; bf16x8 v; } th, tl;
            const float* wp = Wmat + hd * 1024 + (g4 * 8) * 32 + colbase + l15;
            #pragma unroll
            for (int i = 0; i < 8; ++i) {
                float wvv = wp[i * 32];
                __bf16 hi = (__bf16)wvv;
                th.v[i] = hi;
                tl.v[i] = (__bf16)(wvv - (float)hi);
            }
            bH = th.u; bL = tl.u;
        }

        #pragma unroll 1
        for (int t = 0; t < 8; ++t) {
            const float* hp = hn + (size_t)(g * 128 + t * 16 + l15) * 32 + g4 * 8;
            float4 a0 = *(const float4*)(hp);
            float4 a1v = *(const float4*)(hp + 4);
            union { u32x4 u; bf16x8 v; } axh, axl;
            axh.v[0]=(__bf16)a0.x;  axl.v[0]=(__bf16)(a0.x-(float)axh.v[0]);
            axh.v[1]=(__bf16)a0.y;  axl.v[1]=(__bf16)(a0.y-(float)axh.v[1]);
            axh.v[2]=(__bf16)a0.z;  axl.v[2]=(__bf16)(a0.z-(float)axh.v[2]);
            axh.v[3]=(__bf16)a0.w;  axl.v[3]=(__bf16)(a0.w-(float)axh.v[3]);
            axh.v[4]=(__bf16)a1v.x; axl.v[4]=(__bf16)(a1v.x-(float)axh.v[4]);
            axh.v[5]=(__bf16)a1v.y; axl.v[5]=(__bf16)(a1v.y-(float)axh.v[5]);
            axh.v[6]=(__bf16)a1v.z; axl.v[6]=(__bf16)(a1v.z-(float)axh.v[6]);
            axh.v[7]=(__bf16)a1v.w; axl.v[7]=(__bf16)(a1v.w-(float)axh.v[7]);

            f32x4 cc = __builtin_amdgcn_mfma_f32_16x16x32_bf16(
                axh.v, __builtin_bit_cast(bf16x8, bH), (f32x4)(0.f), 0, 0, 0);
            cc = __builtin_amdgcn_mfma_f32_16x16x32_bf16(
                axl.v, __builtin_bit_cast(bf16x8, bH), cc, 0, 0, 0);
            cc = __builtin_amdgcn_mfma_f32_16x16x32_bf16(
                axh.v, __builtin_bit_cast(bf16x8, bL), cc, 0, 0, 0);

            const int r0 = t * 16 + g4 * 4;
            const int col = colbase + l15;
            if (!isFD) {
                FSf[fsoff(r0 + 0) + col] = cc[0];
                FSf[fsoff(r0 + 1) + col] = cc[1];
                FSf[fsoff(r0 + 2) + col] = cc[2];
                FSf[fsoff(r0 + 3) + col] = cc[3];
            } else {
                FD[r0 + 0][col] = cc[0];
                FD[r0 + 1][col] = cc[1];
                FD[r0 + 2][col] = cc[2];
                FD[r0 + 3][col] = cc[3];
            }
        }
    }
    __syncthreads();

    if (tid < 128) {
        float ss = 0.f, sd = 0.f;
        const float* fr = FSf + fsoff(tid);
        #pragma unroll
        for (int oo = 0; oo < 32; ++oo) {
            int o = (oo + tid) & 31;
            float a = AVr[o];
            ss = fmaf(a, fr[o], ss);
            sd = fmaf(a, FD[tid][o], sd);
        }
        As06[tid] = 0.6f * ss;
        Ad06[tid] = 0.6f * sd;
    }
    __syncthreads();

    const int p = tid >> 2, sq = tid & 3, sbase = sq << 5;
    const int d0 = p, d1 = p + 64;
    float fdr0[32], fdr1[32], avs[32];
    #pragma unroll
    for (int c = 0; c < 8; ++c) {
        float4 v0 = *(const float4*)&FD[d0][c * 4];
        fdr0[c*4+0] = v0.x; fdr0[c*4+1] = v0.y; fdr0[c*4+2] = v0.z; fdr0[c*4+3] = v0.w;
        float4 v1 = *(const float4*)&FD[d1][c * 4];
        fdr1[c*4+0] = v1.x; fdr1[c*4+1] = v1.y; fdr1[c*4+2] = v1.z; fdr1[c*4+3] = v1.w;
        float4 wv = *(const float4*)&AVr[c * 4];
        avs[c*4+0] = 0.4f * wv.x; avs[c*4+1] = 0.4f * wv.y;
        avs[c*4+2] = 0.4f * wv.z; avs[c*4+3] = 0.4f * wv.w;
    }
    const float adc0 = Ad06[d0], adc1 = Ad06[d1];

    float Z0 = 0.f, Z1 = 0.f;
    float acc0[32], acc1[32];
    #pragma unroll
    for (int o = 0; o < 32; ++o) { acc0[o] = 0.f; acc1[o] = 0.f; }
    #pragma unroll 1
    for (int si = 0; si < 32; ++si) {
        const int s = sbase + si;
        const float* fr = FSf + fsoff(s);
        float4 fa[8];
        #pragma unroll
        for (int c = 0; c < 8; ++c) fa[c] = *(const float4*)(fr + c * 4);
        float c00 = 0.f, c01 = 0.f, c02 = 0.f, c03 = 0.f;
        float c10 = 0.f, c11 = 0.f, c12 = 0.f, c13 = 0.f;
        #pragma unroll
        for (int c = 0; c < 8; ++c) {
            float e;
            e = fdr0[c*4+0] + fa[c].x; c00 = fmaf(avs[c*4+0], __builtin_fabsf(e), c00);
            e = fdr1[c*4+0] + fa[c].x; c10 = fmaf(avs[c*4+0], __builtin_fabsf(e), c10);
            e = fdr0[c*4+1] + fa[c].y; c01 = fmaf(avs[c*4+1], __builtin_fabsf(e), c01);
            e = fdr1[c*4+1] + fa[c].y; c11 = fmaf(avs[c*4+1], __builtin_fabsf(e), c11);
            e = fdr0[c*4+2] + fa[c].z; c02 = fmaf(avs[c*4+2], __builtin_fabsf(e), c02);
            e = fdr1[c*4+2] + fa[c].z; c12 = fmaf(avs[c*4+2], __builtin_fabsf(e), c12);
            e = fdr0[c*4+3] + fa[c].w; c03 = fmaf(avs[c*4+3], __builtin_fabsf(e), c03);
            e = fdr1[c*4+3] + fa[c].w; c13 = fmaf(avs[c*4+3], __builtin_fabsf(e), c13);
        }
        const float ass = As06[s];
        float v0 = adc0 + ass + ((c00 + c01) + (c02 + c03));
        float v1 = adc1 + ass + ((c10 + c11) + (c12 + c13));
        float e0 = (s == d0) ? 0.f : __expf(v0);
        float e1 = (s == d1) ? 0.f : __expf(v1);
        Z0 += e0; Z1 += e1;
        #pragma unroll
        for (int c = 0; c < 8; ++c) {
            acc0[c*4+0] = fmaf(e0, fa[c].x, acc0[c*4+0]);
            acc1[c*4+0] = fmaf(e1, fa[c].x, acc1[c*4+0]);
            acc0[c*4+1] = fmaf(e0, fa[c].y, acc0[c*4+1]);
            acc1[c*4+1] = fmaf(e1, fa[c].y, acc1[c*4+1]);
            acc0[c*4+2] = fmaf(e0, fa[c].z, acc0[c*4+2]);
            acc1[c*4+2] = fmaf(e1, fa[c].z, acc1[c*4+2]);
            acc0[c*4+3] = fmaf(e0, fa[c].w, acc0[c*4+3]);
            acc1[c*4+3] = fmaf(e1, fa[c].w, acc1[c*4+3]);
        }
    }
    Z0 += __shfl_xor(Z0, 1); Z0 += __shfl_xor(Z0, 2);
    Z1 += __shfl_xor(Z1, 1); Z1 += __shfl_xor(Z1, 2);
    const float rz0 = fast_rcp(Z0), rz1 = fast_rcp(Z1);
    #pragma unroll
    for (int o = 0; o < 32; ++o) {
        acc0[o] += __shfl_xor(acc0[o], 1);
        acc0[o] += __shfl_xor(acc0[o], 2);
        acc1[o] += __shfl_xor(acc1[o], 1);
        acc1[o] += __shfl_xor(acc1[o], 2);
    }

    if (sq == 0) {
        const float* bp = b1 + hd * 32;
        float* dst0 = h1heads + ((size_t)((g * 8 + hd) * 128 + d0)) * 32;
        float* dst1 = h1heads + ((size_t)((g * 8 + hd) * 128 + d1)) * 32;
        #pragma unroll
        for (int c = 0; c < 8; ++c) {
            float4 v;
            v.x = fmaf(acc0[c*4+0], rz0, bp[c*4+0]);
            v.y = fmaf(acc0[c*4+1], rz0, bp[c*4+1]);
            v.z = fmaf(acc0[c*4+2], rz0, bp[c*4+2]);
            v.w = fmaf(acc0[c*4+3], rz0, bp[c*4+3]);
            *(float4*)(dst0 + c * 4) = v;
            v.x = fmaf(acc1[c*4+0], rz1, bp[c*4+0]);
            v.y = fmaf(acc1[c*4+1], rz1, bp[c*4+1]);
            v.z = fmaf(acc1[c*4+2], rz1, bp[c*4+2]);
            v.w = fmaf(acc1[c*4+3], rz1, bp[c*4+3]);
            *(float4*)(dst1 + c * 4) = v;
        }
    }
}

// ---------------------------------------------------------------------------
// GATv2 layer 2, single-pass, staggered FS: one block per graph, 256 threads.
// ---------------------------------------------------------------------------
__global__ __launch_bounds__(256) void gat2_kernel(
    const float* __restrict__ h1heads, const float* __restrict__ W2s,
    const float* __restrict__ W2d, const float* __restrict__ a2,
    const float* __restrict__ b2, float* __restrict__ pooled)
{
    const int g = blockIdx.x;
    __shared__ float HS[128][36];
    __shared__ float FSf[128 * 36 + 16];
    __shared__ float FD[128][36];     // reused as OUT after the fused pass
    __shared__ float AVr[32];
    __shared__ float As06[128];
    __shared__ float Ad06[128];
    const int tid = threadIdx.x;

    if (tid < 32) AVr[tid] = a2[tid];

    {
        #pragma unroll
        for (int i = 0; i < 4; ++i) {
            int idx4 = i * 256 + tid;
            float sx = 0.f, sy = 0.f, sz = 0.f, sw = 0.f;
            #pragma unroll
            for (int hdd = 0; hdd < 8; ++hdd) {
                const float4* src = (const float4*)(h1heads + (size_t)(g * 8 + hdd) * 4096);
                float4 v = src[idx4];
                sx += v.x; sy += v.y; sz += v.z; sw += v.w;
            }
            int n = idx4 >> 3, k0 = (idx4 & 7) * 4;
            float4 r; r.x = sx * 0.125f; r.y = sy * 0.125f; r.z = sz * 0.125f; r.w = sw * 0.125f;
            *(float4*)&HS[n][k0] = r;
        }
    }
    __syncthreads();

    {
        const int o = tid & 31, nb = tid >> 5;
        float wcs[32], wcd[32];
        const float* wsp = W2s + o;
        const float* wdp = W2d + o;
        #pragma unroll
        for (int k = 0; k < 32; ++k) { wcs[k] = wsp[k * 32]; wcd[k] = wdp[k * 32]; }
        #pragma unroll 1
        for (int n = nb * 16; n < nb * 16 + 16; ++n) {
            float a0 = 0.f, a1_ = 0.f, b0 = 0.f, b1_ = 0.f;
            #pragma unroll
            for (int k0 = 0; k0 < 32; k0 += 4) {
                const float4 hv = *(const float4*)&HS[n][k0];
                a0 = fmaf(hv.x, wcs[k0+0], a0); b0 = fmaf(hv.x, wcd[k0+0], b0);
                a1_ = fmaf(hv.y, wcs[k0+1], a1_); b1_ = fmaf(hv.y, wcd[k0+1], b1_);
                a0 = fmaf(hv.z, wcs[k0+2], a0); b0 = fmaf(hv.z, wcd[k0+2], b0);
                a1_ = fmaf(hv.w, wcs[k0+3], a1_); b1_ = fmaf(hv.w, wcd[k0+3], b1_);
            }
            FSf[fsoff(n) + o] = a0 + a1_;
            FD[n][o] = b0 + b1_;
        }
    }
    __syncthreads();

    if (tid < 128) {
        float ss = 0.f, sd = 0.f;
        const float* fr = FSf + fsoff(tid);
        #pragma unroll
        for (int oo = 0; oo < 32; ++oo) {
            int o = (oo + tid) & 31;
            float a = AVr[o];
            ss = fmaf(a, fr[o], ss);
            sd = fmaf(a, FD[tid][o], sd);
        }
        As06[tid] = 0.6f * ss;
        Ad06[tid] = 0.6f * sd;
    }
    __syncthreads();

    const int d = tid >> 1, sbase = (tid & 1) << 6;
    float fdr[32], avs[32];
    #pragma unroll
    for (int c = 0; c < 8; ++c) {
        float4 v = *(const float4*)&FD[d][c * 4];
        fdr[c*4+0] = v.x; fdr[c*4+1] = v.y; fdr[c*4+2] = v.z; fdr[c*4+3] = v.w;
        float4 wv = *(const float4*)&AVr[c * 4];
        avs[c*4+0] = 0.4f * wv.x; avs[c*4+1] = 0.4f * wv.y;
        avs[c*4+2] = 0.4f * wv.z; avs[c*4+3] = 0.4f * wv.w;
    }
    const float adc = Ad06[d];

    float Z = 0.f;
    float acc[32];
    #pragma unroll
    for (int o = 0; o < 32; ++o) acc[o] = 0.f;
    #pragma unroll 1
    for (int si = 0; si < 64; ++si) {
        const int s = sbase + si;
        const float* fr = FSf + fsoff(s);
        float4 fa[8];
        #pragma unroll
        for (int c = 0; c < 8; ++c) fa[c] = *(const float4*)(fr + c * 4);
        float c0 = 0.f, c1 = 0.f, c2 = 0.f, c3 = 0.f;
        #pragma unroll
        for (int c = 0; c < 8; ++c) {
            float e0 = fdr[c*4+0] + fa[c].x; c0 = fmaf(avs[c*4+0], __builtin_fabsf(e0), c0);
            float e1 = fdr[c*4+1] + fa[c].y; c1 = fmaf(avs[c*4+1], __builtin_fabsf(e1), c1);
            float e2 = fdr[c*4+2] + fa[c].z; c2 = fmaf(avs[c*4+2], __builtin_fabsf(e2), c2);
            float e3 = fdr[c*4+3] + fa[c].w; c3 = fmaf(avs[c*4+3], __builtin_fabsf(e3), c3);
        }
        float v = adc + As06[s] + ((c0 + c1) + (c2 + c3));
        float e = (s == d) ? 0.f : __expf(v);
        Z += e;
        #pragma unroll
        for (int c = 0; c < 8; ++c) {
            acc[c*4+0] = fmaf(e, fa[c].x, acc[c*4+0]);
            acc[c*4+1] = fmaf(e, fa[c].y, acc[c*4+1]);
            acc[c*4+2] = fmaf(e, fa[c].z, acc[c*4+2]);
            acc[c*4+3] = fmaf(e, fa[c].w, acc[c*4+3]);
        }
    }
    Z += __shfl_xor(Z, 1);
    const float rz = fast_rcp(Z);
    #pragma unroll
    for (int o = 0; o < 32; ++o) acc[o] += __shfl_xor(acc[o], 1);

    __syncthreads();
    if ((tid & 1) == 0) {
        #pragma unroll
        for (int c = 0; c < 4; ++c) {
            float4 v;
            v.x = acc[c*4+0] * rz; v.y = acc[c*4+1] * rz;
            v.z = acc[c*4+2] * rz; v.w = acc[c*4+3] * rz;
            *(float4*)&FD[d][c * 4] = v;
        }
    } else {
        #pragma unroll
        for (int c = 4; c < 8; ++c) {
            float4 v;
            v.x = acc[c*4+0] * rz; v.y = acc[c*4+1] * rz;
            v.z = acc[c*4+2] * rz; v.w = acc[c*4+3] * rz;
            *(float4*)&FD[d][c * 4] = v;
        }
    }
    __syncthreads();

    if (tid < 32) {
        float sp = 0.f;
        #pragma unroll 1
        for (int n = 0; n < 128; ++n) sp += FD[n][tid];
        pooled[g * 32 + tid] = fmaf(sp, 1.f / 128.f, b2[tid]);
    }
}

// ---------------------------------------------------------------------------
// Final: cosine sims, contrastive loss, output assembly.
// ---------------------------------------------------------------------------
__global__ void final_kernel(const float* __restrict__ pooled,
                             const float* __restrict__ hideout,
                             const float* __restrict__ timestep,
                             float* __restrict__ out)
{
    const int b = threadIdx.x;
    __shared__ float lossArr[16];
    if (b < 16) {
        const float* A  = pooled + b * 32;
        const float* Pv = pooled + (16 + b) * 32;
        float av[32];
        float na = 0.f;
        #pragma unroll
        for (int i = 0; i < 32; ++i) { av[i] = A[i]; na += av[i] * av[i]; }
        float npv = 0.f, dp = 0.f;
        #pragma unroll
        for (int i = 0; i < 32; ++i) { float p = Pv[i]; npv += p * p; dp += av[i] * p; }
        const float eps = 1e-6f;
        const float ia = 1.f / fmaxf(sqrtf(na), eps);
        const float sp = dp * ia / fmaxf(sqrtf(npv), eps);
        float sn[4];
        #pragma unroll
        for (int k = 0; k < 4; ++k) {
            const float* Nv = pooled + (32 + b * 4 + k) * 32;
            float nn = 0.f, dn = 0.f;
            #pragma unroll
            for (int i = 0; i < 32; ++i) { float q = Nv[i]; nn += q * q; dn += av[i] * q; }
            sn[k] = dn * ia / fmaxf(sqrtf(nn), eps);
        }
        float m = sp;
        #pragma unroll
        for (int k = 0; k < 4; ++k) m = fmaxf(m, sn[k]);
        float Z = expf(sp - m);
        #pragma unroll
        for (int k = 0; k < 4; ++k) Z += expf(sn[k] - m);
        lossArr[b] = logf(Z) + m - sp;
        float* r = out + b * 35;
        #pragma unroll
        for (int i = 0; i < 32; ++i) r[i] = av[i];
        r[32] = hideout[b * 2];
        r[33] = hideout[b * 2 + 1];
        r[34] = timestep[b];
    }
    __syncthreads();
    if (b == 0) {
        float s = 0.f;
        #pragma unroll
        for (int i = 0; i < 16; ++i) s += lossArr[i];
        out[560] = s * (1.f / 16.f);
    }
}

extern "C" void kernel_launch(void* const* d_in, const int* in_sizes, int n_in,
                              void* d_out, int out_size, void* d_ws, size_t ws_size,
                              hipStream_t stream) {
    const float* anchor   = (const float*)d_in[0];
    const float* pos      = (const float*)d_in[1];
    const float* neg      = (const float*)d_in[2];
    const float* hideout  = (const float*)d_in[3];
    const float* timestep = (const float*)d_in[4];
    const float* Wih      = (const float*)d_in[5];
    const float* Whh      = (const float*)d_in[6];
    const float* b_lstm   = (const float*)d_in[7];
    const float* W1s      = (const float*)d_in[8];
    const float* W1d      = (const float*)d_in[9];
    const float* a1       = (const float*)d_in[10];
    const float* b1       = (const float*)d_in[11];
    const float* W2s      = (const float*)d_in[12];
    const float* W2d      = (const float*)d_in[13];
    const float* a2       = (const float*)d_in[14];
    const float* b2       = (const float*)d_in[15];
    float* out = (float*)d_out;

    char* ws = (char*)d_ws;
    float* hn      = (float*)(ws);                       // 12288*32*4   = 1,572,864 B
    float* h1heads = (float*)(ws + 1605632);             // 96*8*128*32*4 = 12,582,912 B
    float* pooled  = (float*)(ws + 14188544);            // 96*32*4      = 12,288 B

    hipLaunchKernelGGL(lstm_mfma_kernel, dim3(768), dim3(512), 0, stream,
                       anchor, pos, neg, Wih, Whh, b_lstm, hn);
    hipLaunchKernelGGL(gat1_kernel,  dim3(768),  dim3(256), 0, stream,
                       hn, W1s, W1d, a1, b1, h1heads);
    hipLaunchKernelGGL(gat2_kernel,  dim3(96),   dim3(256), 0, stream,
                       h1heads, W2s, W2d, a2, b2, pooled);
    hipLaunchKernelGGL(final_kernel, dim3(1),    dim3(64),  0, stream,
                       pooled, hideout, timestep, out);
}

// Round 20
// 147.225 us; speedup vs baseline: 1.2057x; 1.2057x over previous
//
#include <hip/hip_runtime.h>
#include <math.h>

// Problem constants: B=16, K=4, T=64, N=128, F=16, H=32, NH=8, GH=32
// Sequences: 12288 = 2048 anchor + 2048 pos + 8192 neg. Graphs: 96 = 16+16+64.

typedef __bf16 bf16x8 __attribute__((ext_vector_type(8)));
typedef float  f32x4  __attribute__((ext_vector_type(4)));
typedef unsigned int u32x4 __attribute__((ext_vector_type(4)));

__device__ __forceinline__ float fast_rcp(float x) { return __builtin_amdgcn_rcpf(x); }
__device__ __forceinline__ float sigm(float x)     { return fast_rcp(1.f + __expf(-x)); }
__device__ __forceinline__ float tanh_fast(float x){ return fmaf(2.f, fast_rcp(1.f + __expf(-2.f * x)), -1.f); }

#define KEEP4(x) asm volatile("" : "+v"(x))

// ---------------------------------------------------------------------------
// LSTM via MFMA, 8-wave gate-split (best measured configuration, R18).
// Block = 512 threads owns 16 sequences; wave w computes ONE z-tile
// (gate G=w>>1, half Hh=w&1): 3 MFMAs -> 4x ds_write_b32 into bank-exact Zl
// (row stride 36, tile stride 592). Activation thread owns one (seq,unit):
// 4 ds_read_b32, 10 trans ops. Hbuf chunk swizzle row&7.
// 3 MFMAs/tile: ax*wih_hi + ahi*whh_hi + ahi*whh_lo (h_lo dropped, ~1e-3).
// ---------------------------------------------------------------------------
__global__ __launch_bounds__(512, 1) void lstm_mfma_kernel(
    const float* __restrict__ anchor, const float* __restrict__ pos,
    const float* __restrict__ neg, const float* __restrict__ Wih,
    const float* __restrict__ Whh, const float* __restrict__ bias,
    float* __restrict__ hn)
{
    __shared__ float Zl[8 * 592];           // [tile][m*36 + u], 18.5 KB
    __shared__ unsigned int Hbuf[2][512];   // [dbuf][16 m][32 j], 4 KB
    const int tid  = threadIdx.x;
    const int w    = tid >> 6;      // wave id = z-tile id
    const int lane = tid & 63;
    const int l15  = lane & 15;
    const int g4   = lane >> 4;
    const int am   = tid >> 5;      // activation role: seq 0..15
    const int aj   = tid & 31;      // activation role: unit 0..31

    #pragma unroll
    for (int i = 0; i < 2; ++i) ((unsigned int*)Hbuf)[tid + i * 512] = 0u;

    // Weights: this wave's single tile (gate G, unit-half Hh)
    const int G = w >> 1, Hh = w & 1;
    const int c = G * 32 + Hh * 16 + l15;
    u32x4 whhH, whhL, wihH;
    {
        union { u32x4 u; bf16x8 v; } th, tl, ti;
        const float* wr = Whh + c * 32 + g4 * 8;
        #pragma unroll
        for (int i = 0; i < 8; ++i) {
            float wv = wr[i];
            __bf16 hi = (__bf16)wv;
            th.v[i] = hi;
            tl.v[i] = (__bf16)(wv - (float)hi);
        }
        if (g4 < 2) {
            const float* wr2 = Wih + c * 16 + g4 * 8;
            #pragma unroll
            for (int i = 0; i < 8; ++i) ti.v[i] = (__bf16)wr2[i];
        } else {
            #pragma unroll
            for (int i = 0; i < 8; ++i) ti.v[i] = (__bf16)0.f;
        }
        whhH = th.u; whhL = tl.u; wihH = ti.u;
    }
    KEEP4(whhH); KEEP4(whhL); KEEP4(wihH);

    // Activation-role bias (one (seq,unit) pair per thread)
    const float bi = bias[aj], bf_ = bias[32 + aj], bg = bias[64 + aj], bo = bias[96 + aj];

    // x source: seq = blk*16 + l15 (all 8 waves load the same x -> L1 hits)
    const int s = blockIdx.x * 16 + l15;
    const float* xbase; int sl;
    if (s < 2048)      { xbase = anchor; sl = s; }
    else if (s < 4096) { xbase = pos;    sl = s - 2048; }
    else               { xbase = neg;    sl = s - 4096; }
    const bool xact = (g4 < 2);
    const float* xp = xbase + (sl >> 7) * 131072 + (sl & 127) * 16 + (xact ? g4 * 8 : 0);

    const float4 z4 = make_float4(0.f, 0.f, 0.f, 0.f);
    float4 xaA = z4, xbA = z4, xaB = z4, xbB = z4;
    if (xact) {
        xaA = *(const float4*)(xp);        xbA = *(const float4*)(xp + 4);
        xaB = *(const float4*)(xp + 2048); xbB = *(const float4*)(xp + 2052);
    }

    float cstA = 0.f, hA = 0.f;     // per activation-thread state

    // Addresses.  Hbuf chunk swizzle: physical chunk = logical ^ (row & 7).
    const int c0  = g4 * 2;
    const int swz = l15 & 7;
    const int ro0 = l15 * 32 + ((c0 ^ swz) << 2);
    const int ro1 = l15 * 32 + (((c0 + 1) ^ swz) << 2);
    const int zw  = w * 592 + (g4 * 4) * 36 + l15;       // z write base (f32 idx)
    const int tHh = aj >> 4, jc = am * 36 + (aj & 15);   // z read offset
    const int zr_i = (0 | tHh) * 592 + jc;
    const int zr_f = (2 | tHh) * 592 + jc;
    const int zr_g = (4 | tHh) * 592 + jc;
    const int zr_o = (6 | tHh) * 592 + jc;
    const int hw   = am * 32 + (((aj >> 2) ^ (am & 7)) << 2) + (aj & 3);
    int cur = 0;
    __syncthreads();

    #define LSTM_STEP(XA, XB)                                                          \
    {                                                                                  \
        bf16x8 ax;                                                                     \
        ax[0]=(__bf16)XA.x; ax[1]=(__bf16)XA.y; ax[2]=(__bf16)XA.z; ax[3]=(__bf16)XA.w;\
        ax[4]=(__bf16)XB.x; ax[5]=(__bf16)XB.y; ax[6]=(__bf16)XB.z; ax[7]=(__bf16)XB.w;\
        uint4 v0 = *(const uint4*)(Hbuf[cur] + ro0);                                   \
        uint4 v1 = *(const uint4*)(Hbuf[cur] + ro1);                                   \
        union { unsigned int u[4]; bf16x8 v; } ahi;                                    \
        ahi.u[0] = __builtin_amdgcn_perm(v0.y, v0.x, 0x05040100u);                     \
        ahi.u[1] = __builtin_amdgcn_perm(v0.w, v0.z, 0x05040100u);                     \
        ahi.u[2] = __builtin_amdgcn_perm(v1.y, v1.x, 0x05040100u);                     \
        ahi.u[3] = __builtin_amdgcn_perm(v1.w, v1.z, 0x05040100u);                     \
        f32x4 a = __builtin_amdgcn_mfma_f32_16x16x32_bf16(                             \
            ax, __builtin_bit_cast(bf16x8, wihH), (f32x4)(0.f), 0, 0, 0);              \
        a = __builtin_amdgcn_mfma_f32_16x16x32_bf16(                                   \
            ahi.v, __builtin_bit_cast(bf16x8, whhH), a, 0, 0, 0);                      \
        a = __builtin_amdgcn_mfma_f32_16x16x32_bf16(                                   \
            ahi.v, __builtin_bit_cast(bf16x8, whhL), a, 0, 0, 0);                      \
        Zl[zw]       = a[0];                                                           \
        Zl[zw + 36]  = a[1];                                                           \
        Zl[zw + 72]  = a[2];                                                           \
        Zl[zw + 108] = a[3];                                                           \
        __syncthreads();                                                               \
        float zi = Zl[zr_i] + bi;                                                      \
        float zf = Zl[zr_f] + bf_;                                                     \
        float zg = Zl[zr_g] + bg;                                                      \
        float zo = Zl[zr_o] + bo;                                                      \
        float cn = fmaf(sigm(zf), cstA, sigm(zi) * tanh_fast(zg));                     \
        cstA = cn;                                                                     \
        hA = sigm(zo) * tanh_fast(cn);                                                 \
        Hbuf[cur ^ 1][hw] = (unsigned int)__builtin_bit_cast(unsigned short,           \
                                                             (__bf16)hA);             \
        __syncthreads();                                                               \
        cur ^= 1;                                                                      \
    }

    for (int t = 0; t < 64; t += 2) {
        float4 cA1 = xaA, cA2 = xbA;
        if (xact && t + 2 < 64) {
            const float* p = xp + (t + 2) * 2048;
            xaA = *(const float4*)(p); xbA = *(const float4*)(p + 4);
        }
        LSTM_STEP(cA1, cA2);

        float4 cB1 = xaB, cB2 = xbB;
        if (xact && t + 3 < 64) {
            const float* p = xp + (t + 3) * 2048;
            xaB = *(const float4*)(p); xbB = *(const float4*)(p + 4);
        }
        LSTM_STEP(cB1, cB2);
    }
    #undef LSTM_STEP

    // epilogue: each thread writes its (seq, unit)
    hn[(blockIdx.x * 16 + am) * 32 + aj] = hA;
}

// FS layout: 4-float shim every 32 rows -> concurrently-read rows land in
// distinct bank groups for all splits used below.
__device__ __forceinline__ int fsoff(int n) { return n * 36 + ((n >> 5) << 2); }

// ---------------------------------------------------------------------------
// GATv2 layer 1: 768 blocks = (graph, head); 256 threads.
// Phase A on MFMA: 4 waves; wave w owns (matrix = w>>1: 0=FS,1=FD,
// col-half = (w&1)*16). B = W columns split bf16 hi/lo; per 16-row tile:
// 2x float4 h loads -> hi/lo A-fragments -> 3 MFMAs (drop lo*lo) -> 4 scalar
// LDS stores via C/D map (col=lane&15, row=(lane>>4)*4+r) [HW-verified].
// Fused pass: TWO d-rows per thread sharing one fa row read; lrelu split
// a.lrelu(e) = 0.6 a.e + 0.4 a.|e|; no-max-shift exp is safe.
// ---------------------------------------------------------------------------
__global__ __launch_bounds__(256, 2) void gat1_kernel(
    const float* __restrict__ hn, const float* __restrict__ W1s,
    const float* __restrict__ W1d, const float* __restrict__ a1,
    const float* __restrict__ b1, float* __restrict__ h1heads)
{
    const int g = blockIdx.x >> 3, hd = blockIdx.x & 7;
    __shared__ float FSf[128 * 36 + 16];
    __shared__ float FD[128][36];
    __shared__ float AVr[32];
    __shared__ float As06[128];
    __shared__ float Ad06[128];
    const int tid = threadIdx.x;

    if (tid < 32) AVr[tid] = a1[hd * 32 + tid];

    // Phase A via MFMA
    {
        const int wv = tid >> 6, lane = tid & 63;
        const int l15 = lane & 15, g4 = lane >> 4;
        const int colbase = (wv & 1) * 16;
        const bool isFD = (wv >> 1) != 0;
        const float* Wmat = isFD ? W1d : W1s;

        u32x4 bH, bL;
        {
            union { u32x4 u; bf16x8 v; } th, tl;
            const float* wp = Wmat + hd * 1024 + (g4 * 8) * 32 + colbase + l15;
            #pragma unroll
            for (int i = 0; i < 8; ++i) {
                float wvv = wp[i * 32];
                __bf16 hi = (__bf16)wvv;
                th.v[i] = hi;
                tl.v[i] = (__bf16)(wvv - (float)hi);
            }
            bH = th.u; bL = tl.u;
        }

        #pragma unroll 1
        for (int t = 0; t < 8; ++t) {
            const float* hp = hn + (size_t)(g * 128 + t * 16 + l15) * 32 + g4 * 8;
            float4 a0 = *(const float4*)(hp);
            float4 a1v = *(const float4*)(hp + 4);
            union { u32x4 u; bf16x8 v; } axh, axl;
            axh.v[0]=(__bf16)a0.x;  axl.v[0]=(__bf16)(a0.x-(float)axh.v[0]);
            axh.v[1]=(__bf16)a0.y;  axl.v[1]=(__bf16)(a0.y-(float)axh.v[1]);
            axh.v[2]=(__bf16)a0.z;  axl.v[2]=(__bf16)(a0.z-(float)axh.v[2]);
            axh.v[3]=(__bf16)a0.w;  axl.v[3]=(__bf16)(a0.w-(float)axh.v[3]);
            axh.v[4]=(__bf16)a1v.x; axl.v[4]=(__bf16)(a1v.x-(float)axh.v[4]);
            axh.v[5]=(__bf16)a1v.y; axl.v[5]=(__bf16)(a1v.y-(float)axh.v[5]);
            axh.v[6]=(__bf16)a1v.z; axl.v[6]=(__bf16)(a1v.z-(float)axh.v[6]);
            axh.v[7]=(__bf16)a1v.w; axl.v[7]=(__bf16)(a1v.w-(float)axh.v[7]);

            f32x4 cc = __builtin_amdgcn_mfma_f32_16x16x32_bf16(
                axh.v, __builtin_bit_cast(bf16x8, bH), (f32x4)(0.f), 0, 0, 0);
            cc = __builtin_amdgcn_mfma_f32_16x16x32_bf16(
                axl.v, __builtin_bit_cast(bf16x8, bH), cc, 0, 0, 0);
            cc = __builtin_amdgcn_mfma_f32_16x16x32_bf16(
                axh.v, __builtin_bit_cast(bf16x8, bL), cc, 0, 0, 0);

            const int r0 = t * 16 + g4 * 4;
            const int col = colbase + l15;
            if (!isFD) {
                FSf[fsoff(r0 + 0) + col] = cc[0];
                FSf[fsoff(r0 + 1) + col] = cc[1];
                FSf[fsoff(r0 + 2) + col] = cc[2];
                FSf[fsoff(r0 + 3) + col] = cc[3];
            } else {
                FD[r0 + 0][col] = cc[0];
                FD[r0 + 1][col] = cc[1];
                FD[r0 + 2][col] = cc[2];
                FD[r0 + 3][col] = cc[3];
            }
        }
    }
    __syncthreads();

    if (tid < 128) {
        float ss = 0.f, sd = 0.f;
        const float* fr = FSf + fsoff(tid);
        #pragma unroll
        for (int oo = 0; oo < 32; ++oo) {
            int o = (oo + tid) & 31;
            float a = AVr[o];
            ss = fmaf(a, fr[o], ss);
            sd = fmaf(a, FD[tid][o], sd);
        }
        As06[tid] = 0.6f * ss;
        Ad06[tid] = 0.6f * sd;
    }
    __syncthreads();

    const int p = tid >> 2, sq = tid & 3, sbase = sq << 5;
    const int d0 = p, d1 = p + 64;
    float fdr0[32], fdr1[32], avs[32];
    #pragma unroll
    for (int c = 0; c < 8; ++c) {
        float4 v0 = *(const float4*)&FD[d0][c * 4];
        fdr0[c*4+0] = v0.x; fdr0[c*4+1] = v0.y; fdr0[c*4+2] = v0.z; fdr0[c*4+3] = v0.w;
        float4 v1 = *(const float4*)&FD[d1][c * 4];
        fdr1[c*4+0] = v1.x; fdr1[c*4+1] = v1.y; fdr1[c*4+2] = v1.z; fdr1[c*4+3] = v1.w;
        float4 wv = *(const float4*)&AVr[c * 4];
        avs[c*4+0] = 0.4f * wv.x; avs[c*4+1] = 0.4f * wv.y;
        avs[c*4+2] = 0.4f * wv.z; avs[c*4+3] = 0.4f * wv.w;
    }
    const float adc0 = Ad06[d0], adc1 = Ad06[d1];

    float Z0 = 0.f, Z1 = 0.f;
    float acc0[32], acc1[32];
    #pragma unroll
    for (int o = 0; o < 32; ++o) { acc0[o] = 0.f; acc1[o] = 0.f; }
    #pragma unroll 1
    for (int si = 0; si < 32; ++si) {
        const int s = sbase + si;
        const float* fr = FSf + fsoff(s);
        float4 fa[8];
        #pragma unroll
        for (int c = 0; c < 8; ++c) fa[c] = *(const float4*)(fr + c * 4);
        float c00 = 0.f, c01 = 0.f, c02 = 0.f, c03 = 0.f;
        float c10 = 0.f, c11 = 0.f, c12 = 0.f, c13 = 0.f;
        #pragma unroll
        for (int c = 0; c < 8; ++c) {
            float e;
            e = fdr0[c*4+0] + fa[c].x; c00 = fmaf(avs[c*4+0], __builtin_fabsf(e), c00);
            e = fdr1[c*4+0] + fa[c].x; c10 = fmaf(avs[c*4+0], __builtin_fabsf(e), c10);
            e = fdr0[c*4+1] + fa[c].y; c01 = fmaf(avs[c*4+1], __builtin_fabsf(e), c01);
            e = fdr1[c*4+1] + fa[c].y; c11 = fmaf(avs[c*4+1], __builtin_fabsf(e), c11);
            e = fdr0[c*4+2] + fa[c].z; c02 = fmaf(avs[c*4+2], __builtin_fabsf(e), c02);
            e = fdr1[c*4+2] + fa[c].z; c12 = fmaf(avs[c*4+2], __builtin_fabsf(e), c12);
            e = fdr0[c*4+3] + fa[c].w; c03 = fmaf(avs[c*4+3], __builtin_fabsf(e), c03);
            e = fdr1[c*4+3] + fa[c].w; c13 = fmaf(avs[c*4+3], __builtin_fabsf(e), c13);
        }
        const float ass = As06[s];
        float v0 = adc0 + ass + ((c00 + c01) + (c02 + c03));
        float v1 = adc1 + ass + ((c10 + c11) + (c12 + c13));
        float e0 = (s == d0) ? 0.f : __expf(v0);
        float e1 = (s == d1) ? 0.f : __expf(v1);
        Z0 += e0; Z1 += e1;
        #pragma unroll
        for (int c = 0; c < 8; ++c) {
            acc0[c*4+0] = fmaf(e0, fa[c].x, acc0[c*4+0]);
            acc1[c*4+0] = fmaf(e1, fa[c].x, acc1[c*4+0]);
            acc0[c*4+1] = fmaf(e0, fa[c].y, acc0[c*4+1]);
            acc1[c*4+1] = fmaf(e1, fa[c].y, acc1[c*4+1]);
            acc0[c*4+2] = fmaf(e0, fa[c].z, acc0[c*4+2]);
            acc1[c*4+2] = fmaf(e1, fa[c].z, acc1[c*4+2]);
            acc0[c*4+3] = fmaf(e0, fa[c].w, acc0[c*4+3]);
            acc1[c*4+3] = fmaf(e1, fa[c].w, acc1[c*4+3]);
        }
    }
    Z0 += __shfl_xor(Z0, 1); Z0 += __shfl_xor(Z0, 2);
    Z1 += __shfl_xor(Z1, 1); Z1 += __shfl_xor(Z1, 2);
    const float rz0 = fast_rcp(Z0), rz1 = fast_rcp(Z1);
    #pragma unroll
    for (int o = 0; o < 32; ++o) {
        acc0[o] += __shfl_xor(acc0[o], 1);
        acc0[o] += __shfl_xor(acc0[o], 2);
        acc1[o] += __shfl_xor(acc1[o], 1);
        acc1[o] += __shfl_xor(acc1[o], 2);
    }

    if (sq == 0) {
        const float* bp = b1 + hd * 32;
        float* dst0 = h1heads + ((size_t)((g * 8 + hd) * 128 + d0)) * 32;
        float* dst1 = h1heads + ((size_t)((g * 8 + hd) * 128 + d1)) * 32;
        #pragma unroll
        for (int c = 0; c < 8; ++c) {
            float4 v;
            v.x = fmaf(acc0[c*4+0], rz0, bp[c*4+0]);
            v.y = fmaf(acc0[c*4+1], rz0, bp[c*4+1]);
            v.z = fmaf(acc0[c*4+2], rz0, bp[c*4+2]);
            v.w = fmaf(acc0[c*4+3], rz0, bp[c*4+3]);
            *(float4*)(dst0 + c * 4) = v;
            v.x = fmaf(acc1[c*4+0], rz1, bp[c*4+0]);
            v.y = fmaf(acc1[c*4+1], rz1, bp[c*4+1]);
            v.z = fmaf(acc1[c*4+2], rz1, bp[c*4+2]);
            v.w = fmaf(acc1[c*4+3], rz1, bp[c*4+3]);
            *(float4*)(dst1 + c * 4) = v;
        }
    }
}

// ---------------------------------------------------------------------------
// GATv2 layer 2, single-pass, staggered FS: one block per graph, 256 threads.
// ---------------------------------------------------------------------------
__global__ __launch_bounds__(256) void gat2_kernel(
    const float* __restrict__ h1heads, const float* __restrict__ W2s,
    const float* __restrict__ W2d, const float* __restrict__ a2,
    const float* __restrict__ b2, float* __restrict__ pooled)
{
    const int g = blockIdx.x;
    __shared__ float HS[128][36];
    __shared__ float FSf[128 * 36 + 16];
    __shared__ float FD[128][36];     // reused as OUT after the fused pass
    __shared__ float AVr[32];
    __shared__ float As06[128];
    __shared__ float Ad06[128];
    const int tid = threadIdx.x;

    if (tid < 32) AVr[tid] = a2[tid];

    {
        #pragma unroll
        for (int i = 0; i < 4; ++i) {
            int idx4 = i * 256 + tid;
            float sx = 0.f, sy = 0.f, sz = 0.f, sw = 0.f;
            #pragma unroll
            for (int hdd = 0; hdd < 8; ++hdd) {
                const float4* src = (const float4*)(h1heads + (size_t)(g * 8 + hdd) * 4096);
                float4 v = src[idx4];
                sx += v.x; sy += v.y; sz += v.z; sw += v.w;
            }
            int n = idx4 >> 3, k0 = (idx4 & 7) * 4;
            float4 r; r.x = sx * 0.125f; r.y = sy * 0.125f; r.z = sz * 0.125f; r.w = sw * 0.125f;
            *(float4*)&HS[n][k0] = r;
        }
    }
    __syncthreads();

    {
        const int o = tid & 31, nb = tid >> 5;
        float wcs[32], wcd[32];
        const float* wsp = W2s + o;
        const float* wdp = W2d + o;
        #pragma unroll
        for (int k = 0; k < 32; ++k) { wcs[k] = wsp[k * 32]; wcd[k] = wdp[k * 32]; }
        #pragma unroll 1
        for (int n = nb * 16; n < nb * 16 + 16; ++n) {
            float a0 = 0.f, a1_ = 0.f, b0 = 0.f, b1_ = 0.f;
            #pragma unroll
            for (int k0 = 0; k0 < 32; k0 += 4) {
                const float4 hv = *(const float4*)&HS[n][k0];
                a0 = fmaf(hv.x, wcs[k0+0], a0); b0 = fmaf(hv.x, wcd[k0+0], b0);
                a1_ = fmaf(hv.y, wcs[k0+1], a1_); b1_ = fmaf(hv.y, wcd[k0+1], b1_);
                a0 = fmaf(hv.z, wcs[k0+2], a0); b0 = fmaf(hv.z, wcd[k0+2], b0);
                a1_ = fmaf(hv.w, wcs[k0+3], a1_); b1_ = fmaf(hv.w, wcd[k0+3], b1_);
            }
            FSf[fsoff(n) + o] = a0 + a1_;
            FD[n][o] = b0 + b1_;
        }
    }
    __syncthreads();

    if (tid < 128) {
        float ss = 0.f, sd = 0.f;
        const float* fr = FSf + fsoff(tid);
        #pragma unroll
        for (int oo = 0; oo < 32; ++oo) {
            int o = (oo + tid) & 31;
            float a = AVr[o];
            ss = fmaf(a, fr[o], ss);
            sd = fmaf(a, FD[tid][o], sd);
        }
        As06[tid] = 0.6f * ss;
        Ad06[tid] = 0.6f * sd;
    }
    __syncthreads();

    const int d = tid >> 1, sbase = (tid & 1) << 6;
    float fdr[32], avs[32];
    #pragma unroll
    for (int c = 0; c < 8; ++c) {
        float4 v = *(const float4*)&FD[d][c * 4];
        fdr[c*4+0] = v.x; fdr[c*4+1] = v.y; fdr[c*4+2] = v.z; fdr[c*4+3] = v.w;
        float4 wv = *(const float4*)&AVr[c * 4];
        avs[c*4+0] = 0.4f * wv.x; avs[c*4+1] = 0.4f * wv.y;
        avs[c*4+2] = 0.4f * wv.z; avs[c*4+3] = 0.4f * wv.w;
    }
    const float adc = Ad06[d];

    float Z = 0.f;
    float acc[32];
    #pragma unroll
    for (int o = 0; o < 32; ++o) acc[o] = 0.f;
    #pragma unroll 1
    for (int si = 0; si < 64; ++si) {
        const int s = sbase + si;
        const float* fr = FSf + fsoff(s);
        float4 fa[8];
        #pragma unroll
        for (int c = 0; c < 8; ++c) fa[c] = *(const float4*)(fr + c * 4);
        float c0 = 0.f, c1 = 0.f, c2 = 0.f, c3 = 0.f;
        #pragma unroll
        for (int c = 0; c < 8; ++c) {
            float e0 = fdr[c*4+0] + fa[c].x; c0 = fmaf(avs[c*4+0], __builtin_fabsf(e0), c0);
            float e1 = fdr[c*4+1] + fa[c].y; c1 = fmaf(avs[c*4+1], __builtin_fabsf(e1), c1);
            float e2 = fdr[c*4+2] + fa[c].z; c2 = fmaf(avs[c*4+2], __builtin_fabsf(e2), c2);
            float e3 = fdr[c*4+3] + fa[c].w; c3 = fmaf(avs[c*4+3], __builtin_fabsf(e3), c3);
        }
        float v = adc + As06[s] + ((c0 + c1) + (c2 + c3));
        float e = (s == d) ? 0.f : __expf(v);
        Z += e;
        #pragma unroll
        for (int c = 0; c < 8; ++c) {
            acc[c*4+0] = fmaf(e, fa[c].x, acc[c*4+0]);
            acc[c*4+1] = fmaf(e, fa[c].y, acc[c*4+1]);
            acc[c*4+2] = fmaf(e, fa[c].z, acc[c*4+2]);
            acc[c*4+3] = fmaf(e, fa[c].w, acc[c*4+3]);
        }
    }
    Z += __shfl_xor(Z, 1);
    const float rz = fast_rcp(Z);
    #pragma unroll
    for (int o = 0; o < 32; ++o) acc[o] += __shfl_xor(acc[o], 1);

    __syncthreads();
    if ((tid & 1) == 0) {
        #pragma unroll
        for (int c = 0; c < 4; ++c) {
            float4 v;
            v.x = acc[c*4+0] * rz; v.y = acc[c*4+1] * rz;
            v.z = acc[c*4+2] * rz; v.w = acc[c*4+3] * rz;
            *(float4*)&FD[d][c * 4] = v;
        }
    } else {
        #pragma unroll
        for (int c = 4; c < 8; ++c) {
            float4 v;
            v.x = acc[c*4+0] * rz; v.y = acc[c*4+1] * rz;
            v.z = acc[c*4+2] * rz; v.w = acc[c*4+3] * rz;
            *(float4*)&FD[d][c * 4] = v;
        }
    }
    __syncthreads();

    if (tid < 32) {
        float sp = 0.f;
        #pragma unroll 1
        for (int n = 0; n < 128; ++n) sp += FD[n][tid];
        pooled[g * 32 + tid] = fmaf(sp, 1.f / 128.f, b2[tid]);
    }
}

// ---------------------------------------------------------------------------
// Final: cosine sims, contrastive loss, output assembly.
// ---------------------------------------------------------------------------
__global__ void final_kernel(const float* __restrict__ pooled,
                             const float* __restrict__ hideout,
                             const float* __restrict__ timestep,
                             float* __restrict__ out)
{
    const int b = threadIdx.x;
    __shared__ float lossArr[16];
    if (b < 16) {
        const float* A  = pooled + b * 32;
        const float* Pv = pooled + (16 + b) * 32;
        float av[32];
        float na = 0.f;
        #pragma unroll
        for (int i = 0; i < 32; ++i) { av[i] = A[i]; na += av[i] * av[i]; }
        float npv = 0.f, dp = 0.f;
        #pragma unroll
        for (int i = 0; i < 32; ++i) { float p = Pv[i]; npv += p * p; dp += av[i] * p; }
        const float eps = 1e-6f;
        const float ia = 1.f / fmaxf(sqrtf(na), eps);
        const float sp = dp * ia / fmaxf(sqrtf(npv), eps);
        float sn[4];
        #pragma unroll
        for (int k = 0; k < 4; ++k) {
            const float* Nv = pooled + (32 + b * 4 + k) * 32;
            float nn = 0.f, dn = 0.f;
            #pragma unroll
            for (int i = 0; i < 32; ++i) { float q = Nv[i]; nn += q * q; dn += av[i] * q; }
            sn[k] = dn * ia / fmaxf(sqrtf(nn), eps);
        }
        float m = sp;
        #pragma unroll
        for (int k = 0; k < 4; ++k) m = fmaxf(m, sn[k]);
        float Z = expf(sp - m);
        #pragma unroll
        for (int k = 0; k < 4; ++k) Z += expf(sn[k] - m);
        lossArr[b] = logf(Z) + m - sp;
        float* r = out + b * 35;
        #pragma unroll
        for (int i = 0; i < 32; ++i) r[i] = av[i];
        r[32] = hideout[b * 2];
        r[33] = hideout[b * 2 + 1];
        r[34] = timestep[b];
    }
    __syncthreads();
    if (b == 0) {
        float s = 0.f;
        #pragma unroll
        for (int i = 0; i < 16; ++i) s += lossArr[i];
        out[560] = s * (1.f / 16.f);
    }
}

extern "C" void kernel_launch(void* const* d_in, const int* in_sizes, int n_in,
                              void* d_out, int out_size, void* d_ws, size_t ws_size,
                              hipStream_t stream) {
    const float* anchor   = (const float*)d_in[0];
    const float* pos      = (const float*)d_in[1];
    const float* neg      = (const float*)d_in[2];
    const float* hideout  = (const float*)d_in[3];
    const float* timestep = (const float*)d_in[4];
    const float* Wih      = (const float*)d_in[5];
    const float* Whh      = (const float*)d_in[6];
    const float* b_lstm   = (const float*)d_in[7];
    const float* W1s      = (const float*)d_in[8];
    const float* W1d      = (const float*)d_in[9];
    const float* a1       = (const float*)d_in[10];
    const float* b1       = (const float*)d_in[11];
    const float* W2s      = (const float*)d_in[12];
    const float* W2d      = (const float*)d_in[13];
    const float* a2       = (const float*)d_in[14];
    const float* b2       = (const float*)d_in[15];
    float* out = (float*)d_out;

    char* ws = (char*)d_ws;
    float* hn      = (float*)(ws);                       // 12288*32*4   = 1,572,864 B
    float* h1heads = (float*)(ws + 1605632);             // 96*8*128*32*4 = 12,582,912 B
    float* pooled  = (float*)(ws + 14188544);            // 96*32*4      = 12,288 B

    hipLaunchKernelGGL(lstm_mfma_kernel, dim3(768), dim3(512), 0, stream,
                       anchor, pos, neg, Wih, Whh, b_lstm, hn);
    hipLaunchKernelGGL(gat1_kernel,  dim3(768),  dim3(256), 0, stream,
                       hn, W1s, W1d, a1, b1, h1heads);
    hipLaunchKernelGGL(gat2_kernel,  dim3(96),   dim3(256), 0, stream,
                       h1heads, W2s, W2d, a2, b2, pooled);
    hipLaunchKernelGGL(final_kernel, dim3(1),    dim3(64),  0, stream,
                       pooled, hideout, timestep, out);
}